// Round 1
// baseline (53142.004 us; speedup 1.0000x reference)
//
#include <hip/hip_runtime.h>

typedef unsigned short u16;
typedef _Float16 f16;
typedef f16 half8 __attribute__((ext_vector_type(8)));
typedef float float4v __attribute__((ext_vector_type(4)));

union HV { uint4 u; half8 h; u16 s[8]; };

__device__ __forceinline__ float h2f(u16 u) { union { u16 u; f16 h; } c; c.u = u; return (float)c.h; }
__device__ __forceinline__ u16 f2h(float f) { union { u16 u; f16 h; } c; c.h = (f16)f; return c.u; }

// ---------------- fp32 -> fp16 convert ----------------
__global__ void cvt_f32_f16(const float* __restrict__ s, u16* __restrict__ d, int n) {
  for (int i = blockIdx.x * blockDim.x + threadIdx.x; i < n; i += gridDim.x * blockDim.x)
    d[i] = f2h(s[i]);
}

// ---------------- GEMM: C[M][2048] = A[M][K] * B[2048][K]^T (fp16 in/out, fp32 accum) ----------
// grid: (N/128, M/128), block 256 (4 waves, 2x2 of 64x64)
__global__ __launch_bounds__(256) void gemm_f16(const u16* __restrict__ A, const u16* __restrict__ B,
                                                u16* __restrict__ C, int K) {
  __shared__ u16 As[128][40];
  __shared__ u16 Bs[128][40];
  const int tid = threadIdx.x, lane = tid & 63, wid = tid >> 6;
  const int col = lane & 15, quad = lane >> 4;
  const int wm = (wid & 1) * 64, wn = (wid >> 1) * 64;
  const int n0 = blockIdx.x * 128;
  const int m0 = blockIdx.y * 128;
  float4v acc[4][4];
  #pragma unroll
  for (int i = 0; i < 4; ++i)
    #pragma unroll
    for (int j = 0; j < 4; ++j) acc[i][j] = (float4v){0.f, 0.f, 0.f, 0.f};

  const int srow = tid >> 2;           // 0..63
  const int schunk = (tid & 3) * 8;    // 0,8,16,24

  for (int k0 = 0; k0 < K; k0 += 32) {
    __syncthreads();
    #pragma unroll
    for (int r2 = 0; r2 < 2; ++r2) {
      int row = srow + 64 * r2;
      int kk = k0 + schunk;
      uint4 av = {0, 0, 0, 0}, bv = {0, 0, 0, 0};
      if (kk + 8 <= K) {
        av = *(const uint4*)(A + (size_t)(m0 + row) * K + kk);
        bv = *(const uint4*)(B + (size_t)(n0 + row) * K + kk);
      }
      *(uint4*)&As[row][schunk] = av;
      *(uint4*)&Bs[row][schunk] = bv;
    }
    __syncthreads();
    HV af[4], bf[4];
    #pragma unroll
    for (int i = 0; i < 4; ++i) af[i].u = *(const uint4*)&As[wm + i * 16 + col][quad * 8];
    #pragma unroll
    for (int j = 0; j < 4; ++j) bf[j].u = *(const uint4*)&Bs[wn + j * 16 + col][quad * 8];
    #pragma unroll
    for (int i = 0; i < 4; ++i)
      #pragma unroll
      for (int j = 0; j < 4; ++j)
        acc[i][j] = __builtin_amdgcn_mfma_f32_16x16x32_f16(af[i].h, bf[j].h, acc[i][j], 0, 0, 0);
  }
  #pragma unroll
  for (int i = 0; i < 4; ++i)
    #pragma unroll
    for (int j = 0; j < 4; ++j)
      #pragma unroll
      for (int r = 0; r < 4; ++r) {
        int m = m0 + wm + i * 16 + quad * 4 + r;
        int n = n0 + wn + j * 16 + col;
        C[(size_t)m * 2048 + n] = f2h(acc[i][j][r]);
      }
}

// ---------------- BatchNorm stats over 32000 rows ----------------
__global__ void bn_stats(const u16* __restrict__ C, float* __restrict__ acc) {
  int c = blockIdx.x * 256 + threadIdx.x;  // 0..2047
  int r0 = blockIdx.y * 256;
  float s = 0.f, q = 0.f;
  for (int r = r0; r < r0 + 256; ++r) {
    float v = h2f(C[(size_t)r * 2048 + c]);
    s += v; q += v * v;
  }
  atomicAdd(&acc[2 * c], s);
  atomicAdd(&acc[2 * c + 1], q);
}

__global__ void bn_final(const float* __restrict__ acc, const float* __restrict__ g,
                         const float* __restrict__ b, float2* __restrict__ ss) {
  int c = blockIdx.x * 256 + threadIdx.x;
  float mean = acc[2 * c] * (1.f / 32000.f);
  float var = acc[2 * c + 1] * (1.f / 32000.f) - mean * mean;
  float sc = g[c] * rsqrtf(var + 1e-5f);
  float2 o; o.x = sc; o.y = b[c] - mean * sc;
  ss[c] = o;
}

// ---------------- persistent recurrence ----------------
// 64 blocks x 256 threads (co-resident). Block beta owns h-cols [16b,16b+16) i.e. gate cols
// {16b..} (a) and {1024+16b..} (z). Waves: (mh = batch half, kh = K half). U frags in VGPRs.
__device__ __forceinline__ void grid_barrier(unsigned* cnt, unsigned target) {
  __syncthreads();
  if (threadIdx.x == 0) {
    __threadfence();  // release: publish this block's stores/atomics device-wide
    __hip_atomic_fetch_add(cnt, 1u, __ATOMIC_RELAXED, __HIP_MEMORY_SCOPE_AGENT);
    while (__hip_atomic_load(cnt, __ATOMIC_RELAXED, __HIP_MEMORY_SCOPE_AGENT) < target)
      __builtin_amdgcn_s_sleep(1);
    __threadfence();  // acquire: invalidate stale L1/L2 before re-reading shared state
  }
  __syncthreads();
}

template <int OUT_F32>
__global__ __launch_bounds__(256, 1) void rec_kernel(
    const u16* __restrict__ w,      // [32*1000][2048] fp16 (pre-BN)
    const float2* __restrict__ ss,  // [2048] BN scale/shift
    const u16* __restrict__ U,      // [2048][1024] fp16
    u16* hbuf,                      // [32][1024] fp16 (current h, shared)
    float* slots,                   // [2][32][2] LN stat accumulators
    unsigned* cnt,                  // barrier counter
    u16* out16, float* out32) {
  const int tid = threadIdx.x, lane = tid & 63, wid = tid >> 6;
  const int mh = wid & 1, kh = wid >> 1;
  const int beta = blockIdx.x;
  const int col = lane & 15, quad = lane >> 4;
  __shared__ float4v red[2][2][64];

  const int ja = beta * 16 + col;   // a gate col == h col owned by this lane
  const int jz = 1024 + ja;         // paired z gate col

  HV uf0[16], uf1[16];              // U fragments, resident in registers (128 VGPRs)
  #pragma unroll
  for (int kk = 0; kk < 16; ++kk) {
    int k = kh * 512 + kk * 32 + quad * 8;
    uf0[kk].u = *(const uint4*)(U + (size_t)ja * 1024 + k);
    uf1[kk].u = *(const uint4*)(U + (size_t)jz * 1024 + k);
  }
  float2 ssa = ss[ja], ssz = ss[jz];
  float hreg[4] = {0.f, 0.f, 0.f, 0.f};  // fp32 master copy of owned h (4 batches x 1 col)
  unsigned bar = 0;

  for (int t = 0; t < 1000; ++t) {
    // ---- phase A: uh = h @ U^T for owned cols (M=32 batches, N=32 gate cols, K split 2) ----
    HV af[16];
    {
      const int b0 = mh * 16 + col;
      const int kb = kh * 512 + quad * 8;
      #pragma unroll
      for (int kk = 0; kk < 16; ++kk)
        af[kk].u = *(const uint4*)(hbuf + b0 * 1024 + kb + kk * 32);
    }
    float4v a0 = (float4v){0, 0, 0, 0}, a1 = (float4v){0, 0, 0, 0};
    #pragma unroll
    for (int kk = 0; kk < 16; ++kk) {
      a0 = __builtin_amdgcn_mfma_f32_16x16x32_f16(af[kk].h, uf0[kk].h, a0, 0, 0, 0);
      a1 = __builtin_amdgcn_mfma_f32_16x16x32_f16(af[kk].h, uf1[kk].h, a1, 0, 0, 0);
    }
    if (kh == 1) { red[mh][0][lane] = a0; red[mh][1][lane] = a1; }
    __syncthreads();
    const int p = t & 1;
    u16 wra[4], wrz[4];
    if (kh == 0) {
      a0 += red[mh][0][lane];
      a1 += red[mh][1][lane];
      // local LN-stat partials over this block's 32 gate cols, per batch row
      #pragma unroll
      for (int r = 0; r < 4; ++r) {
        float sv = a0[r] + a1[r];
        float qv = a0[r] * a0[r] + a1[r] * a1[r];
        #pragma unroll
        for (int off = 1; off < 16; off <<= 1) {
          sv += __shfl_xor(sv, off, 64);
          qv += __shfl_xor(qv, off, 64);
        }
        if (col == 0) {
          int b = mh * 16 + quad * 4 + r;
          atomicAdd(&slots[p * 64 + 2 * b], sv);
          atomicAdd(&slots[p * 64 + 2 * b + 1], qv);
        }
      }
      // prefetch w for this step (completes during barrier's vmcnt drain)
      #pragma unroll
      for (int r = 0; r < 4; ++r) {
        int b = mh * 16 + quad * 4 + r;
        size_t wrow = ((size_t)b * 1000 + t) * 2048;
        wra[r] = w[wrow + ja];
        wrz[r] = w[wrow + jz];
      }
    }
    grid_barrier(cnt, 64u * (++bar));  // B1: stats complete
    // ---- phase B: LN + gates + h update (owned cols, lane-local a/z pairing) ----
    if (kh == 0) {
      #pragma unroll
      for (int r = 0; r < 4; ++r) {
        int b = mh * 16 + quad * 4 + r;
        float sm = slots[p * 64 + 2 * b];
        float sq = slots[p * 64 + 2 * b + 1];
        float mean = sm * (1.f / 2048.f);
        float var = sq * (1.f / 2048.f) - mean * mean;
        float inv = rsqrtf(var + 1e-5f);
        float ga = h2f(wra[r]) * ssa.x + ssa.y + (a0[r] - mean) * inv;
        float gz = h2f(wrz[r]) * ssz.x + ssz.y + (a1[r] - mean) * inv;
        float z = 1.f / (1.f + __expf(-gz));
        float rl = ga > 0.f ? ga : 0.f;
        float h = z * hreg[r] + (1.f - z) * rl;
        hreg[r] = h;
        hbuf[b * 1024 + ja] = f2h(h);
        size_t orow = ((size_t)b * 1000 + t) * 1024 + ja;
        if (OUT_F32) out32[orow] = h; else out16[orow] = f2h(h);
      }
    } else if (beta == 0 && wid == 2) {
      slots[((t + 1) & 1) * 64 + lane] = 0.f;  // zero next step's stat slot
    }
    grid_barrier(cnt, 64u * (++bar));  // B2: new h published
  }
}

extern "C" void kernel_launch(void* const* d_in, const int* in_sizes, int n_in,
                              void* d_out, int out_size, void* d_ws, size_t ws_size,
                              hipStream_t stream) {
  (void)in_sizes; (void)n_in; (void)out_size;
  const float* x  = (const float*)d_in[0];
  const float* W1 = (const float*)d_in[1];
  const float* U1 = (const float*)d_in[2];
  const float* g1 = (const float*)d_in[3];
  const float* b1 = (const float*)d_in[4];
  const float* W2 = (const float*)d_in[5];
  const float* U2 = (const float*)d_in[6];
  const float* g2 = (const float*)d_in[7];
  const float* b2 = (const float*)d_in[8];

  char* ws = (char*)d_ws;
  size_t o = 0;
  auto take = [&](size_t bytes) { size_t r = o; o = (o + bytes + 255) & ~(size_t)255; return r; };
  u16* wbuf  = (u16*)(ws + take(32000ULL * 2048 * 2));   // 131 MB, reused by both layers
  u16* h1seq = (u16*)(ws + take(32000ULL * 1024 * 2));   // 65 MB layer-1 output (fp16)
  u16* xb    = (u16*)(ws + take(32000ULL * 80 * 2));
  u16* W1b   = (u16*)(ws + take(2048ULL * 80 * 2));
  u16* W2b   = (u16*)(ws + take(2048ULL * 1024 * 2));
  u16* U1b   = (u16*)(ws + take(2048ULL * 1024 * 2));
  u16* U2b   = (u16*)(ws + take(2048ULL * 1024 * 2));
  float2* ss1 = (float2*)(ws + take(2048 * 8));
  float2* ss2 = (float2*)(ws + take(2048 * 8));
  size_t zbase = o;  // everything below must start zeroed
  float* acc1 = (float*)(ws + take(2048 * 8));
  float* acc2 = (float*)(ws + take(2048 * 8));
  float* slots1 = (float*)(ws + take(512));
  float* slots2 = (float*)(ws + take(512));
  unsigned* cnt1 = (unsigned*)(ws + take(256));
  unsigned* cnt2 = (unsigned*)(ws + take(256));
  u16* hbuf1 = (u16*)(ws + take(32 * 1024 * 2));
  u16* hbuf2 = (u16*)(ws + take(32 * 1024 * 2));
  size_t zlen = o - zbase;
  if (ws_size < o) return;  // workspace too small: fail loudly via validation

  hipMemsetAsync(ws + zbase, 0, zlen, stream);

  cvt_f32_f16<<<1280, 256, 0, stream>>>(x, xb, 32000 * 80);
  cvt_f32_f16<<<160, 256, 0, stream>>>(W1, W1b, 2048 * 80);
  cvt_f32_f16<<<1024, 256, 0, stream>>>(U1, U1b, 2048 * 1024);
  cvt_f32_f16<<<1024, 256, 0, stream>>>(W2, W2b, 2048 * 1024);
  cvt_f32_f16<<<1024, 256, 0, stream>>>(U2, U2b, 2048 * 1024);

  // ---- layer 1 ----
  gemm_f16<<<dim3(16, 250), 256, 0, stream>>>(xb, W1b, wbuf, 80);
  bn_stats<<<dim3(8, 125), 256, 0, stream>>>(wbuf, acc1);
  bn_final<<<8, 256, 0, stream>>>(acc1, g1, b1, ss1);
  rec_kernel<0><<<64, 256, 0, stream>>>(wbuf, ss1, U1b, hbuf1, slots1, cnt1, h1seq, nullptr);

  // ---- layer 2 ----
  gemm_f16<<<dim3(16, 250), 256, 0, stream>>>(h1seq, W2b, wbuf, 1024);
  bn_stats<<<dim3(8, 125), 256, 0, stream>>>(wbuf, acc2);
  bn_final<<<8, 256, 0, stream>>>(acc2, g2, b2, ss2);
  rec_kernel<1><<<64, 256, 0, stream>>>(wbuf, ss2, U2b, hbuf2, slots2, cnt2, nullptr, (float*)d_out);
}

// Round 3
// 20790.361 us; speedup vs baseline: 2.5561x; 2.5561x over previous
//
#include <hip/hip_runtime.h>

typedef unsigned short u16;
typedef _Float16 f16;
typedef f16 half8 __attribute__((ext_vector_type(8)));
typedef float float4v __attribute__((ext_vector_type(4)));

union HV { uint4 u; half8 h; u16 s[8]; };

__device__ __forceinline__ float h2f(u16 u) { union { u16 u; f16 h; } c; c.u = u; return (float)c.h; }
__device__ __forceinline__ u16 f2h(float f) { union { u16 u; f16 h; } c; c.h = (f16)f; return c.u; }

// ---- coherent (cross-XCD) access helpers: sc0 sc1 => operate at LLC, bypass XCD L2 ----
// NOTE: 128-bit vectors are NOT valid as "v" asm *inputs* (clang: "indirect register
// inputs") — scalar inputs and vector *outputs* are fine.
__device__ __forceinline__ void store_coh_u16(u16* p, unsigned v) {
  asm volatile("global_store_short %0, %1, off sc0 sc1" :: "v"(p), "v"(v) : "memory");
}
__device__ __forceinline__ void store_coh_u32(void* p, unsigned v) {
  asm volatile("global_store_dword %0, %1, off sc0 sc1" :: "v"(p), "v"(v) : "memory");
}
__device__ __forceinline__ float4v load_coh_f32x4(const void* p) {
  float4v r;
  asm volatile("global_load_dwordx4 %0, %1, off sc0 sc1\n\ts_waitcnt vmcnt(0)"
               : "=v"(r) : "v"(p) : "memory");
  return r;
}
__device__ __forceinline__ unsigned load_coh_u32(const unsigned* p) {
  unsigned r;
  asm volatile("global_load_dword %0, %1, off sc0 sc1\n\ts_waitcnt vmcnt(0)"
               : "=v"(r) : "v"(p) : "memory");
  return r;
}

// ---------------- fp32 -> fp16 convert ----------------
__global__ void cvt_f32_f16(const float* __restrict__ s, u16* __restrict__ d, int n) {
  for (int i = blockIdx.x * blockDim.x + threadIdx.x; i < n; i += gridDim.x * blockDim.x)
    d[i] = f2h(s[i]);
}

// ---------------- GEMM: C[M][2048] = A[M][K] * B[2048][K]^T (fp16 in/out, fp32 accum) ----------
__global__ __launch_bounds__(256) void gemm_f16(const u16* __restrict__ A, const u16* __restrict__ B,
                                                u16* __restrict__ C, int K) {
  __shared__ u16 As[128][40];
  __shared__ u16 Bs[128][40];
  const int tid = threadIdx.x, lane = tid & 63, wid = tid >> 6;
  const int col = lane & 15, quad = lane >> 4;
  const int wm = (wid & 1) * 64, wn = (wid >> 1) * 64;
  const int n0 = blockIdx.x * 128;
  const int m0 = blockIdx.y * 128;
  float4v acc[4][4];
  #pragma unroll
  for (int i = 0; i < 4; ++i)
    #pragma unroll
    for (int j = 0; j < 4; ++j) acc[i][j] = (float4v){0.f, 0.f, 0.f, 0.f};

  const int srow = tid >> 2;
  const int schunk = (tid & 3) * 8;

  for (int k0 = 0; k0 < K; k0 += 32) {
    __syncthreads();
    #pragma unroll
    for (int r2 = 0; r2 < 2; ++r2) {
      int row = srow + 64 * r2;
      int kk = k0 + schunk;
      uint4 av = {0, 0, 0, 0}, bv = {0, 0, 0, 0};
      if (kk + 8 <= K) {
        av = *(const uint4*)(A + (size_t)(m0 + row) * K + kk);
        bv = *(const uint4*)(B + (size_t)(n0 + row) * K + kk);
      }
      *(uint4*)&As[row][schunk] = av;
      *(uint4*)&Bs[row][schunk] = bv;
    }
    __syncthreads();
    HV af[4], bf[4];
    #pragma unroll
    for (int i = 0; i < 4; ++i) af[i].u = *(const uint4*)&As[wm + i * 16 + col][quad * 8];
    #pragma unroll
    for (int j = 0; j < 4; ++j) bf[j].u = *(const uint4*)&Bs[wn + j * 16 + col][quad * 8];
    #pragma unroll
    for (int i = 0; i < 4; ++i)
      #pragma unroll
      for (int j = 0; j < 4; ++j)
        acc[i][j] = __builtin_amdgcn_mfma_f32_16x16x32_f16(af[i].h, bf[j].h, acc[i][j], 0, 0, 0);
  }
  #pragma unroll
  for (int i = 0; i < 4; ++i)
    #pragma unroll
    for (int j = 0; j < 4; ++j)
      #pragma unroll
      for (int r = 0; r < 4; ++r) {
        int m = m0 + wm + i * 16 + quad * 4 + r;
        int n = n0 + wn + j * 16 + col;
        C[(size_t)m * 2048 + n] = f2h(acc[i][j][r]);
      }
}

// ---------------- BatchNorm stats over 32000 rows ----------------
__global__ void bn_stats(const u16* __restrict__ C, float* __restrict__ acc) {
  int c = blockIdx.x * 256 + threadIdx.x;
  int r0 = blockIdx.y * 256;
  float s = 0.f, q = 0.f;
  for (int r = r0; r < r0 + 256; ++r) {
    float v = h2f(C[(size_t)r * 2048 + c]);
    s += v; q += v * v;
  }
  atomicAdd(&acc[2 * c], s);
  atomicAdd(&acc[2 * c + 1], q);
}

__global__ void bn_final(const float* __restrict__ acc, const float* __restrict__ g,
                         const float* __restrict__ b, float2* __restrict__ ss) {
  int c = blockIdx.x * 256 + threadIdx.x;
  float mean = acc[2 * c] * (1.f / 32000.f);
  float var = acc[2 * c + 1] * (1.f / 32000.f) - mean * mean;
  float sc = g[c] * rsqrtf(var + 1e-5f);
  float2 o; o.x = sc; o.y = b[c] - mean * sc;
  ss[c] = o;
}

// ---------------- persistent recurrence ----------------
// 64 blocks x 256 threads (co-resident). Block beta owns h-cols [16b,16b+16).
// NO fences anywhere: cross-XCD shared state (hbuf, slots, cnt) accessed only via
// sc0|sc1 (LLC-coherent) instructions; __syncthreads drains vmcnt before s_barrier,
// so all coherent stores are globally visible before the barrier arrival add.
__device__ __forceinline__ void grid_barrier(unsigned* cnt, unsigned target) {
  asm volatile("s_waitcnt vmcnt(0)" ::: "memory");  // belt+braces: per-wave drain
  __syncthreads();
  if (threadIdx.x == 0) {
    __hip_atomic_fetch_add(cnt, 1u, __ATOMIC_RELAXED, __HIP_MEMORY_SCOPE_AGENT);
    unsigned v;
    do { v = load_coh_u32(cnt); } while (v < target);
  }
  __syncthreads();
}

// slots layout: float slots[2][32][16] : [phase][batch][ 0..7 = sum by blockgroup,
//                                                        8..15 = sumsq by blockgroup ]
template <int OUT_F32>
__global__ __launch_bounds__(256, 1) void rec_kernel(
    const u16* __restrict__ w,      // [32*1000][2048] fp16 (pre-BN)
    const float2* __restrict__ ss,  // [2048] BN scale/shift
    const u16* __restrict__ U,      // [2048][1024] fp16
    u16* hbuf,                      // [32][1024] fp16 (current h, cross-block shared)
    float* slots,                   // [2][32][16] LN stat accumulators
    unsigned* cnt,                  // barrier counter
    u16* out16, float* out32) {
  const int tid = threadIdx.x, lane = tid & 63, wid = tid >> 6;
  const int mh = wid & 1, kh = wid >> 1;
  const int beta = blockIdx.x;
  const int g = beta >> 3;          // 8-way split of stat accumulation
  const int col = lane & 15, quad = lane >> 4;
  __shared__ float4v red[2][2][64];

  const int ja = beta * 16 + col;   // a gate col == h col owned by this lane
  const int jz = 1024 + ja;         // paired z gate col

  HV uf0[16], uf1[16];              // U fragments resident in registers
  #pragma unroll
  for (int kk = 0; kk < 16; ++kk) {
    int k = kh * 512 + kk * 32 + quad * 8;
    uf0[kk].u = *(const uint4*)(U + (size_t)ja * 1024 + k);
    uf1[kk].u = *(const uint4*)(U + (size_t)jz * 1024 + k);
  }
  float2 ssa = ss[ja], ssz = ss[jz];
  float hreg[4] = {0.f, 0.f, 0.f, 0.f};
  unsigned bar = 0;

  const int b0 = mh * 16 + quad * 4;             // batch group for phase-B lanes
  const u16* aptr = hbuf + (mh * 16 + col) * 1024 + kh * 512 + quad * 8;

  for (int t = 0; t < 1000; ++t) {
    // ---- phase A: uh = h @ U^T (coherent 16B loads of h; M=32, N=32, K split over kh) ----
    HV af[16];
    asm volatile(
        "global_load_dwordx4 %0,  %16, off sc0 sc1\n\t"
        "global_load_dwordx4 %1,  %16, off offset:64  sc0 sc1\n\t"
        "global_load_dwordx4 %2,  %16, off offset:128 sc0 sc1\n\t"
        "global_load_dwordx4 %3,  %16, off offset:192 sc0 sc1\n\t"
        "global_load_dwordx4 %4,  %16, off offset:256 sc0 sc1\n\t"
        "global_load_dwordx4 %5,  %16, off offset:320 sc0 sc1\n\t"
        "global_load_dwordx4 %6,  %16, off offset:384 sc0 sc1\n\t"
        "global_load_dwordx4 %7,  %16, off offset:448 sc0 sc1\n\t"
        "global_load_dwordx4 %8,  %16, off offset:512 sc0 sc1\n\t"
        "global_load_dwordx4 %9,  %16, off offset:576 sc0 sc1\n\t"
        "global_load_dwordx4 %10, %16, off offset:640 sc0 sc1\n\t"
        "global_load_dwordx4 %11, %16, off offset:704 sc0 sc1\n\t"
        "global_load_dwordx4 %12, %16, off offset:768 sc0 sc1\n\t"
        "global_load_dwordx4 %13, %16, off offset:832 sc0 sc1\n\t"
        "global_load_dwordx4 %14, %16, off offset:896 sc0 sc1\n\t"
        "global_load_dwordx4 %15, %16, off offset:960 sc0 sc1\n\t"
        "s_waitcnt vmcnt(0)"
        : "=v"(af[0].u), "=v"(af[1].u), "=v"(af[2].u), "=v"(af[3].u),
          "=v"(af[4].u), "=v"(af[5].u), "=v"(af[6].u), "=v"(af[7].u),
          "=v"(af[8].u), "=v"(af[9].u), "=v"(af[10].u), "=v"(af[11].u),
          "=v"(af[12].u), "=v"(af[13].u), "=v"(af[14].u), "=v"(af[15].u)
        : "v"(aptr)
        : "memory");

    float4v a0 = (float4v){0, 0, 0, 0}, a1 = (float4v){0, 0, 0, 0};
    #pragma unroll
    for (int kk = 0; kk < 16; ++kk) {
      a0 = __builtin_amdgcn_mfma_f32_16x16x32_f16(af[kk].h, uf0[kk].h, a0, 0, 0, 0);
      a1 = __builtin_amdgcn_mfma_f32_16x16x32_f16(af[kk].h, uf1[kk].h, a1, 0, 0, 0);
    }
    if (kh == 1) { red[mh][0][lane] = a0; red[mh][1][lane] = a1; }
    __syncthreads();
    const int p = t & 1;
    u16 wra[4], wrz[4];
    if (kh == 0) {
      a0 += red[mh][0][lane];
      a1 += red[mh][1][lane];
      // per-batch partial stats over this block's 32 gate cols
      #pragma unroll
      for (int r = 0; r < 4; ++r) {
        float sv = a0[r] + a1[r];
        float qv = a0[r] * a0[r] + a1[r] * a1[r];
        #pragma unroll
        for (int off = 1; off < 16; off <<= 1) {
          sv += __shfl_xor(sv, off, 64);
          qv += __shfl_xor(qv, off, 64);
        }
        if (col == 0) {
          int b = b0 + r;
          atomicAdd(&slots[p * 512 + b * 16 + g], sv);        // device-scope RMW @ LLC
          atomicAdd(&slots[p * 512 + b * 16 + 8 + g], qv);
        }
      }
      // prefetch w for this step (normal cached loads; in flight across the barrier drain)
      #pragma unroll
      for (int r = 0; r < 4; ++r) {
        int b = b0 + r;
        size_t wrow = ((size_t)b * 1000 + t) * 2048;
        wra[r] = w[wrow + ja];
        wrz[r] = w[wrow + jz];
      }
    }
    grid_barrier(cnt, 64u * (++bar));  // B1: stats complete
    // ---- phase B: LN + gates + h update ----
    if (kh == 0) {
      // cooperative stat read: each lane loads one 16B chunk of its quad's 4 batches' stats
      float4v ch = load_coh_f32x4(slots + p * 512 + b0 * 16 + col * 4);
      float ps = ch[0] + ch[1] + ch[2] + ch[3];
      const int q16 = quad * 16;
      #pragma unroll
      for (int r = 0; r < 4; ++r) {
        float sm = __shfl(ps, q16 + 4 * r, 64) + __shfl(ps, q16 + 4 * r + 1, 64);
        float sq = __shfl(ps, q16 + 4 * r + 2, 64) + __shfl(ps, q16 + 4 * r + 3, 64);
        float mean = sm * (1.f / 2048.f);
        float var = sq * (1.f / 2048.f) - mean * mean;
        float inv = rsqrtf(var + 1e-5f);
        float ga = h2f(wra[r]) * ssa.x + ssa.y + (a0[r] - mean) * inv;
        float gz = h2f(wrz[r]) * ssz.x + ssz.y + (a1[r] - mean) * inv;
        float z = 1.f / (1.f + __expf(-gz));
        float rl = ga > 0.f ? ga : 0.f;
        float h = z * hreg[r] + (1.f - z) * rl;
        hreg[r] = h;
        int b = b0 + r;
        store_coh_u16(hbuf + b * 1024 + ja, f2h(h));
        size_t orow = ((size_t)b * 1000 + t) * 1024 + ja;
        if (OUT_F32) out32[orow] = h; else out16[orow] = f2h(h);
      }
    } else if (beta == 0 && wid == 2) {
      // zero next step's stat slots (512 floats): 64 lanes x 8 dword coherent stores
      float* z = slots + ((t + 1) & 1) * 512 + lane * 8;
      #pragma unroll
      for (int i = 0; i < 8; ++i) store_coh_u32(z + i, 0u);
    }
    grid_barrier(cnt, 64u * (++bar));  // B2: new h published
  }
}

extern "C" void kernel_launch(void* const* d_in, const int* in_sizes, int n_in,
                              void* d_out, int out_size, void* d_ws, size_t ws_size,
                              hipStream_t stream) {
  (void)in_sizes; (void)n_in; (void)out_size;
  const float* x  = (const float*)d_in[0];
  const float* W1 = (const float*)d_in[1];
  const float* U1 = (const float*)d_in[2];
  const float* g1 = (const float*)d_in[3];
  const float* b1 = (const float*)d_in[4];
  const float* W2 = (const float*)d_in[5];
  const float* U2 = (const float*)d_in[6];
  const float* g2 = (const float*)d_in[7];
  const float* b2 = (const float*)d_in[8];

  char* ws = (char*)d_ws;
  size_t o = 0;
  auto take = [&](size_t bytes) { size_t r = o; o = (o + bytes + 255) & ~(size_t)255; return r; };
  u16* wbuf  = (u16*)(ws + take(32000ULL * 2048 * 2));   // 131 MB, reused by both layers
  u16* h1seq = (u16*)(ws + take(32000ULL * 1024 * 2));   // 65 MB layer-1 output (fp16)
  u16* xb    = (u16*)(ws + take(32000ULL * 80 * 2));
  u16* W1b   = (u16*)(ws + take(2048ULL * 80 * 2));
  u16* W2b   = (u16*)(ws + take(2048ULL * 1024 * 2));
  u16* U1b   = (u16*)(ws + take(2048ULL * 1024 * 2));
  u16* U2b   = (u16*)(ws + take(2048ULL * 1024 * 2));
  float2* ss1 = (float2*)(ws + take(2048 * 8));
  float2* ss2 = (float2*)(ws + take(2048 * 8));
  size_t zbase = o;  // everything below must start zeroed
  float* acc1 = (float*)(ws + take(2048 * 8));
  float* acc2 = (float*)(ws + take(2048 * 8));
  float* slots1 = (float*)(ws + take(2 * 32 * 16 * 4));
  float* slots2 = (float*)(ws + take(2 * 32 * 16 * 4));
  unsigned* cnt1 = (unsigned*)(ws + take(256));
  unsigned* cnt2 = (unsigned*)(ws + take(256));
  u16* hbuf1 = (u16*)(ws + take(32 * 1024 * 2));
  u16* hbuf2 = (u16*)(ws + take(32 * 1024 * 2));
  size_t zlen = o - zbase;
  if (ws_size < o) return;

  (void)hipMemsetAsync(ws + zbase, 0, zlen, stream);

  cvt_f32_f16<<<1280, 256, 0, stream>>>(x, xb, 32000 * 80);
  cvt_f32_f16<<<160, 256, 0, stream>>>(W1, W1b, 2048 * 80);
  cvt_f32_f16<<<1024, 256, 0, stream>>>(U1, U1b, 2048 * 1024);
  cvt_f32_f16<<<1024, 256, 0, stream>>>(W2, W2b, 2048 * 1024);
  cvt_f32_f16<<<1024, 256, 0, stream>>>(U2, U2b, 2048 * 1024);

  // ---- layer 1 ----
  gemm_f16<<<dim3(16, 250), 256, 0, stream>>>(xb, W1b, wbuf, 80);
  bn_stats<<<dim3(8, 125), 256, 0, stream>>>(wbuf, acc1);
  bn_final<<<8, 256, 0, stream>>>(acc1, g1, b1, ss1);
  rec_kernel<0><<<64, 256, 0, stream>>>(wbuf, ss1, U1b, hbuf1, slots1, cnt1, h1seq, nullptr);

  // ---- layer 2 ----
  gemm_f16<<<dim3(16, 250), 256, 0, stream>>>(h1seq, W2b, wbuf, 1024);
  bn_stats<<<dim3(8, 125), 256, 0, stream>>>(wbuf, acc2);
  bn_final<<<8, 256, 0, stream>>>(acc2, g2, b2, ss2);
  rec_kernel<1><<<64, 256, 0, stream>>>(wbuf, ss2, U2b, hbuf2, slots2, cnt2, nullptr, (float*)d_out);
}

// Round 4
// 15201.791 us; speedup vs baseline: 3.4958x; 1.3676x over previous
//
#include <hip/hip_runtime.h>

typedef unsigned short u16;
typedef _Float16 f16;
typedef f16 half8 __attribute__((ext_vector_type(8)));
typedef float float4v __attribute__((ext_vector_type(4)));

union HV { uint4 u; half8 h; u16 s[8]; };

__device__ __forceinline__ float h2f(u16 u) { union { u16 u; f16 h; } c; c.u = u; return (float)c.h; }
__device__ __forceinline__ u16 f2h(float f) { union { u16 u; f16 h; } c; c.h = (f16)f; return c.u; }

// ---- coherent (cross-XCD) access helpers: sc0 sc1 => operate at LLC, bypass XCD L2 ----
// NOTE: 128-bit vectors are NOT valid as "v" asm *inputs*; scalar inputs and vector
// *outputs* are fine.
__device__ __forceinline__ void store_coh_u16(u16* p, unsigned v) {
  asm volatile("global_store_short %0, %1, off sc0 sc1" :: "v"(p), "v"(v) : "memory");
}
__device__ __forceinline__ void store_coh_u32(void* p, unsigned v) {
  asm volatile("global_store_dword %0, %1, off sc0 sc1" :: "v"(p), "v"(v) : "memory");
}
__device__ __forceinline__ void store_coh_f32(float* p, float v) {
  asm volatile("global_store_dword %0, %1, off sc0 sc1" :: "v"(p), "v"(v) : "memory");
}
__device__ __forceinline__ unsigned load_coh_u32(const unsigned* p) {
  unsigned r;
  asm volatile("global_load_dword %0, %1, off sc0 sc1\n\ts_waitcnt vmcnt(0)"
               : "=v"(r) : "v"(p) : "memory");
  return r;
}

// ---------------- fp32 -> fp16 convert ----------------
__global__ void cvt_f32_f16(const float* __restrict__ s, u16* __restrict__ d, int n) {
  for (int i = blockIdx.x * blockDim.x + threadIdx.x; i < n; i += gridDim.x * blockDim.x)
    d[i] = f2h(s[i]);
}

// ---------------- GEMM: C[M][2048] = A[M][K] * B[2048][K]^T (fp16 in/out, fp32 accum) ----------
__global__ __launch_bounds__(256) void gemm_f16(const u16* __restrict__ A, const u16* __restrict__ B,
                                                u16* __restrict__ C, int K) {
  __shared__ u16 As[128][40];
  __shared__ u16 Bs[128][40];
  const int tid = threadIdx.x, lane = tid & 63, wid = tid >> 6;
  const int col = lane & 15, quad = lane >> 4;
  const int wm = (wid & 1) * 64, wn = (wid >> 1) * 64;
  const int n0 = blockIdx.x * 128;
  const int m0 = blockIdx.y * 128;
  float4v acc[4][4];
  #pragma unroll
  for (int i = 0; i < 4; ++i)
    #pragma unroll
    for (int j = 0; j < 4; ++j) acc[i][j] = (float4v){0.f, 0.f, 0.f, 0.f};

  const int srow = tid >> 2;
  const int schunk = (tid & 3) * 8;

  for (int k0 = 0; k0 < K; k0 += 32) {
    __syncthreads();
    #pragma unroll
    for (int r2 = 0; r2 < 2; ++r2) {
      int row = srow + 64 * r2;
      int kk = k0 + schunk;
      uint4 av = {0, 0, 0, 0}, bv = {0, 0, 0, 0};
      if (kk + 8 <= K) {
        av = *(const uint4*)(A + (size_t)(m0 + row) * K + kk);
        bv = *(const uint4*)(B + (size_t)(n0 + row) * K + kk);
      }
      *(uint4*)&As[row][schunk] = av;
      *(uint4*)&Bs[row][schunk] = bv;
    }
    __syncthreads();
    HV af[4], bf[4];
    #pragma unroll
    for (int i = 0; i < 4; ++i) af[i].u = *(const uint4*)&As[wm + i * 16 + col][quad * 8];
    #pragma unroll
    for (int j = 0; j < 4; ++j) bf[j].u = *(const uint4*)&Bs[wn + j * 16 + col][quad * 8];
    #pragma unroll
    for (int i = 0; i < 4; ++i)
      #pragma unroll
      for (int j = 0; j < 4; ++j)
        acc[i][j] = __builtin_amdgcn_mfma_f32_16x16x32_f16(af[i].h, bf[j].h, acc[i][j], 0, 0, 0);
  }
  #pragma unroll
  for (int i = 0; i < 4; ++i)
    #pragma unroll
    for (int j = 0; j < 4; ++j)
      #pragma unroll
      for (int r = 0; r < 4; ++r) {
        int m = m0 + wm + i * 16 + quad * 4 + r;
        int n = n0 + wn + j * 16 + col;
        C[(size_t)m * 2048 + n] = f2h(acc[i][j][r]);
      }
}

// ---------------- BatchNorm stats over 32000 rows ----------------
__global__ void bn_stats(const u16* __restrict__ C, float* __restrict__ acc) {
  int c = blockIdx.x * 256 + threadIdx.x;
  int r0 = blockIdx.y * 256;
  float s = 0.f, q = 0.f;
  for (int r = r0; r < r0 + 256; ++r) {
    float v = h2f(C[(size_t)r * 2048 + c]);
    s += v; q += v * v;
  }
  atomicAdd(&acc[2 * c], s);
  atomicAdd(&acc[2 * c + 1], q);
}

__global__ void bn_final(const float* __restrict__ acc, const float* __restrict__ g,
                         const float* __restrict__ b, float2* __restrict__ ss) {
  int c = blockIdx.x * 256 + threadIdx.x;
  float mean = acc[2 * c] * (1.f / 32000.f);
  float var = acc[2 * c + 1] * (1.f / 32000.f) - mean * mean;
  float sc = g[c] * rsqrtf(var + 1e-5f);
  float2 o; o.x = sc; o.y = b[c] - mean * sc;
  ss[c] = o;
}

// ---------------- persistent recurrence ----------------
// 64 blocks x 256 threads (co-resident). Block beta owns h-cols [16b,16b+16).
// Synchronization: all-to-all FLAG barrier (no RMW contention): each block stores a
// monotonic epoch to its own 64B-aligned flag; wave 0 polls all 64 flags (one lane
// each) until all >= epoch. All cross-block data via sc0|sc1 (LLC) accesses; every
// wave drains vmcnt before __syncthreads, so stores are globally visible before the
// block's flag store (which happens after the internal barrier).
__device__ __forceinline__ void flag_barrier(unsigned* flags, unsigned epoch, int lane,
                                             int wid, int beta) {
  asm volatile("s_waitcnt vmcnt(0)" ::: "memory");
  __syncthreads();  // all 4 waves drained + arrived
  if (wid == 0) {
    if (lane == 0) store_coh_u32(flags + beta * 16, epoch);
    unsigned v;
    do { v = load_coh_u32(flags + lane * 16); } while (!__all((int)(v >= epoch)));
  }
  __syncthreads();
}

// pstats layout: float pstats[2][32][64][2] : [phase][batch][block][sum,sumsq]
template <int OUT_F32>
__global__ __launch_bounds__(256, 1) void rec_kernel(
    const u16* __restrict__ w,      // [32*1000][2048] fp16 (pre-BN)
    const float2* __restrict__ ss,  // [2048] BN scale/shift
    const u16* __restrict__ U,      // [2048][1024] fp16
    u16* hbuf,                      // [32][1024] fp16 (current h, cross-block shared)
    float* pstats,                  // [2][32][64][2] LN partial stats
    unsigned* flags,                // [64] barrier flags, 64B stride
    u16* out16, float* out32) {
  const int tid = threadIdx.x, lane = tid & 63, wid = tid >> 6;
  const int mh = wid & 1, kh = wid >> 1;
  const int beta = blockIdx.x;
  const int col = lane & 15, quad = lane >> 4;
  __shared__ float4v red[2][2][64];

  const int ja = beta * 16 + col;   // a gate col == h col owned by this lane
  const int jz = 1024 + ja;         // paired z gate col

  HV uf0[16], uf1[16];              // U fragments resident in registers
  #pragma unroll
  for (int kk = 0; kk < 16; ++kk) {
    int k = kh * 512 + kk * 32 + quad * 8;
    uf0[kk].u = *(const uint4*)(U + (size_t)ja * 1024 + k);
    uf1[kk].u = *(const uint4*)(U + (size_t)jz * 1024 + k);
  }
  float2 ssa = ss[ja], ssz = ss[jz];
  float hreg[4] = {0.f, 0.f, 0.f, 0.f};
  unsigned bar = 0;

  const int b0 = mh * 16 + quad * 4;             // batch group for phase-B lanes
  const u16* aptr = hbuf + (mh * 16 + col) * 1024 + kh * 512 + quad * 8;

  for (int t = 0; t < 1000; ++t) {
    // ---- phase A: uh = h @ U^T (coherent 16B loads of h; M=32, N=32, K split over kh) ----
    HV af[16];
    asm volatile(
        "global_load_dwordx4 %0,  %16, off sc0 sc1\n\t"
        "global_load_dwordx4 %1,  %16, off offset:64  sc0 sc1\n\t"
        "global_load_dwordx4 %2,  %16, off offset:128 sc0 sc1\n\t"
        "global_load_dwordx4 %3,  %16, off offset:192 sc0 sc1\n\t"
        "global_load_dwordx4 %4,  %16, off offset:256 sc0 sc1\n\t"
        "global_load_dwordx4 %5,  %16, off offset:320 sc0 sc1\n\t"
        "global_load_dwordx4 %6,  %16, off offset:384 sc0 sc1\n\t"
        "global_load_dwordx4 %7,  %16, off offset:448 sc0 sc1\n\t"
        "global_load_dwordx4 %8,  %16, off offset:512 sc0 sc1\n\t"
        "global_load_dwordx4 %9,  %16, off offset:576 sc0 sc1\n\t"
        "global_load_dwordx4 %10, %16, off offset:640 sc0 sc1\n\t"
        "global_load_dwordx4 %11, %16, off offset:704 sc0 sc1\n\t"
        "global_load_dwordx4 %12, %16, off offset:768 sc0 sc1\n\t"
        "global_load_dwordx4 %13, %16, off offset:832 sc0 sc1\n\t"
        "global_load_dwordx4 %14, %16, off offset:896 sc0 sc1\n\t"
        "global_load_dwordx4 %15, %16, off offset:960 sc0 sc1\n\t"
        "s_waitcnt vmcnt(0)"
        : "=v"(af[0].u), "=v"(af[1].u), "=v"(af[2].u), "=v"(af[3].u),
          "=v"(af[4].u), "=v"(af[5].u), "=v"(af[6].u), "=v"(af[7].u),
          "=v"(af[8].u), "=v"(af[9].u), "=v"(af[10].u), "=v"(af[11].u),
          "=v"(af[12].u), "=v"(af[13].u), "=v"(af[14].u), "=v"(af[15].u)
        : "v"(aptr)
        : "memory");

    float4v a0 = (float4v){0, 0, 0, 0}, a1 = (float4v){0, 0, 0, 0};
    #pragma unroll
    for (int kk = 0; kk < 16; ++kk) {
      a0 = __builtin_amdgcn_mfma_f32_16x16x32_f16(af[kk].h, uf0[kk].h, a0, 0, 0, 0);
      a1 = __builtin_amdgcn_mfma_f32_16x16x32_f16(af[kk].h, uf1[kk].h, a1, 0, 0, 0);
    }
    if (kh == 1) { red[mh][0][lane] = a0; red[mh][1][lane] = a1; }
    __syncthreads();
    const int p = t & 1;
    u16 wra[4], wrz[4];
    if (kh == 0) {
      a0 += red[mh][0][lane];
      a1 += red[mh][1][lane];
      // per-batch partial stats over this block's 32 gate cols -> plain coherent stores
      #pragma unroll
      for (int r = 0; r < 4; ++r) {
        float sv = a0[r] + a1[r];
        float qv = a0[r] * a0[r] + a1[r] * a1[r];
        #pragma unroll
        for (int off = 1; off < 16; off <<= 1) {
          sv += __shfl_xor(sv, off, 64);
          qv += __shfl_xor(qv, off, 64);
        }
        if (col == 0) {
          float* dst = pstats + (((size_t)p * 32 + (b0 + r)) * 64 + beta) * 2;
          store_coh_f32(dst, sv);
          store_coh_f32(dst + 1, qv);
        }
      }
      // prefetch w for this step (normal cached loads; in flight across the barrier)
      #pragma unroll
      for (int r = 0; r < 4; ++r) {
        int b = b0 + r;
        size_t wrow = ((size_t)b * 1000 + t) * 2048;
        wra[r] = w[wrow + ja];
        wrz[r] = w[wrow + jz];
      }
    }
    flag_barrier(flags, ++bar, lane, wid, beta);  // B1: all partial stats visible
    // ---- phase B: LN + gates + h update ----
    if (kh == 0) {
      // gather: batch row = 128 floats (64 blocks x [s,q]); 16 lanes x 32B each,
      // 4 batch rows (stride 512B), one wait for all 8 loads
      float4v c[8];
      const float* rowbase = pstats + ((size_t)p * 32 + b0) * 128 + col * 8;
      asm volatile(
          "global_load_dwordx4 %0, %8, off sc0 sc1\n\t"
          "global_load_dwordx4 %1, %8, off offset:16   sc0 sc1\n\t"
          "global_load_dwordx4 %2, %8, off offset:512  sc0 sc1\n\t"
          "global_load_dwordx4 %3, %8, off offset:528  sc0 sc1\n\t"
          "global_load_dwordx4 %4, %8, off offset:1024 sc0 sc1\n\t"
          "global_load_dwordx4 %5, %8, off offset:1040 sc0 sc1\n\t"
          "global_load_dwordx4 %6, %8, off offset:1536 sc0 sc1\n\t"
          "global_load_dwordx4 %7, %8, off offset:1552 sc0 sc1\n\t"
          "s_waitcnt vmcnt(0)"
          : "=v"(c[0]), "=v"(c[1]), "=v"(c[2]), "=v"(c[3]),
            "=v"(c[4]), "=v"(c[5]), "=v"(c[6]), "=v"(c[7])
          : "v"(rowbase)
          : "memory");
      #pragma unroll
      for (int r = 0; r < 4; ++r) {
        float sm = c[2 * r][0] + c[2 * r][2] + c[2 * r + 1][0] + c[2 * r + 1][2];
        float sq = c[2 * r][1] + c[2 * r][3] + c[2 * r + 1][1] + c[2 * r + 1][3];
        #pragma unroll
        for (int off = 1; off < 16; off <<= 1) {
          sm += __shfl_xor(sm, off, 64);
          sq += __shfl_xor(sq, off, 64);
        }
        float mean = sm * (1.f / 2048.f);
        float var = sq * (1.f / 2048.f) - mean * mean;
        float inv = rsqrtf(var + 1e-5f);
        float ga = h2f(wra[r]) * ssa.x + ssa.y + (a0[r] - mean) * inv;
        float gz = h2f(wrz[r]) * ssz.x + ssz.y + (a1[r] - mean) * inv;
        float z = 1.f / (1.f + __expf(-gz));
        float rl = ga > 0.f ? ga : 0.f;
        float h = z * hreg[r] + (1.f - z) * rl;
        hreg[r] = h;
        int b = b0 + r;
        store_coh_u16(hbuf + b * 1024 + ja, f2h(h));
        size_t orow = ((size_t)b * 1000 + t) * 1024 + ja;
        if (OUT_F32) out32[orow] = h; else out16[orow] = f2h(h);
      }
    }
    flag_barrier(flags, ++bar, lane, wid, beta);  // B2: new h published
  }
}

extern "C" void kernel_launch(void* const* d_in, const int* in_sizes, int n_in,
                              void* d_out, int out_size, void* d_ws, size_t ws_size,
                              hipStream_t stream) {
  (void)in_sizes; (void)n_in; (void)out_size;
  const float* x  = (const float*)d_in[0];
  const float* W1 = (const float*)d_in[1];
  const float* U1 = (const float*)d_in[2];
  const float* g1 = (const float*)d_in[3];
  const float* b1 = (const float*)d_in[4];
  const float* W2 = (const float*)d_in[5];
  const float* U2 = (const float*)d_in[6];
  const float* g2 = (const float*)d_in[7];
  const float* b2 = (const float*)d_in[8];

  char* ws = (char*)d_ws;
  size_t o = 0;
  auto take = [&](size_t bytes) { size_t r = o; o = (o + bytes + 255) & ~(size_t)255; return r; };
  u16* wbuf  = (u16*)(ws + take(32000ULL * 2048 * 2));   // 131 MB, reused by both layers
  u16* h1seq = (u16*)(ws + take(32000ULL * 1024 * 2));   // 65 MB layer-1 output (fp16)
  u16* xb    = (u16*)(ws + take(32000ULL * 80 * 2));
  u16* W1b   = (u16*)(ws + take(2048ULL * 80 * 2));
  u16* W2b   = (u16*)(ws + take(2048ULL * 1024 * 2));
  u16* U1b   = (u16*)(ws + take(2048ULL * 1024 * 2));
  u16* U2b   = (u16*)(ws + take(2048ULL * 1024 * 2));
  float2* ss1 = (float2*)(ws + take(2048 * 8));
  float2* ss2 = (float2*)(ws + take(2048 * 8));
  size_t zbase = o;  // everything below must start zeroed
  float* acc1 = (float*)(ws + take(2048 * 8));
  float* acc2 = (float*)(ws + take(2048 * 8));
  float* pstats1 = (float*)(ws + take(2 * 32 * 64 * 2 * 4));
  float* pstats2 = (float*)(ws + take(2 * 32 * 64 * 2 * 4));
  unsigned* flags1 = (unsigned*)(ws + take(64 * 64));
  unsigned* flags2 = (unsigned*)(ws + take(64 * 64));
  u16* hbuf1 = (u16*)(ws + take(32 * 1024 * 2));
  u16* hbuf2 = (u16*)(ws + take(32 * 1024 * 2));
  size_t zlen = o - zbase;
  if (ws_size < o) return;

  (void)hipMemsetAsync(ws + zbase, 0, zlen, stream);

  cvt_f32_f16<<<1280, 256, 0, stream>>>(x, xb, 32000 * 80);
  cvt_f32_f16<<<160, 256, 0, stream>>>(W1, W1b, 2048 * 80);
  cvt_f32_f16<<<1024, 256, 0, stream>>>(U1, U1b, 2048 * 1024);
  cvt_f32_f16<<<1024, 256, 0, stream>>>(W2, W2b, 2048 * 1024);
  cvt_f32_f16<<<1024, 256, 0, stream>>>(U2, U2b, 2048 * 1024);

  // ---- layer 1 ----
  gemm_f16<<<dim3(16, 250), 256, 0, stream>>>(xb, W1b, wbuf, 80);
  bn_stats<<<dim3(8, 125), 256, 0, stream>>>(wbuf, acc1);
  bn_final<<<8, 256, 0, stream>>>(acc1, g1, b1, ss1);
  rec_kernel<0><<<64, 256, 0, stream>>>(wbuf, ss1, U1b, hbuf1, pstats1, flags1, h1seq, nullptr);

  // ---- layer 2 ----
  gemm_f16<<<dim3(16, 250), 256, 0, stream>>>(h1seq, W2b, wbuf, 1024);
  bn_stats<<<dim3(8, 125), 256, 0, stream>>>(wbuf, acc2);
  bn_final<<<8, 256, 0, stream>>>(acc2, g2, b2, ss2);
  rec_kernel<1><<<64, 256, 0, stream>>>(wbuf, ss2, U2b, hbuf2, pstats2, flags2, nullptr, (float*)d_out);
}